// Round 1
// baseline (8279.394 us; speedup 1.0000x reference)
//
#include <hip/hip_runtime.h>

#define NPIX   512
#define NDET   768
#define NSAMP  768
#define NVIEW  360
#define NBATCH 8

__global__ __launch_bounds__(256) void projector_kernel(
    const float* __restrict__ image,   // [8, 512, 512]
    const float* __restrict__ views,   // [360]
    float* __restrict__ out)           // [8, 360, 768]
{
    const int d = blockIdx.x * blockDim.x + threadIdx.x;
    const int v = blockIdx.y;
    if (d >= NDET) return;

    const float PIX   = 0.7433f;
    const float ISO   = 595.0f;
    const float SDD_  = 595.0f + 490.6f;          // 1085.6
    const float DGAM  = 1.2858f / SDD_;
    const float FOV   = 512.0f * 0.7433f * 0.70710678f;
    const float T0    = ISO - FOV;
    const float DT    = 2.0f * FOV / (float)NSAMP;

    const float beta  = views[v];
    const float gamma = ((float)d - 0.5f * (float)(NDET - 1)) * DGAM;
    const float sx = ISO * cosf(beta);
    const float sy = ISO * sinf(beta);
    const float ang = beta + 3.14159265358979f + gamma;
    const float dirx = cosf(ang);
    const float diry = sinf(ang);

    // pixel-space ray: fx(t) = cx + gx*t, fy(t) = cy + gy*t
    const float gx = dirx / PIX;
    const float gy = diry / PIX;
    const float cx = sx / PIX + 0.5f * (float)(NPIX - 1);
    const float cy = sy / PIX + 0.5f * (float)(NPIX - 1);

    // Clip sample range to padded image box (pad 3 px; outside contributes 0)
    const float PLO = -3.0f, PHI = (float)NPIX + 2.0f;   // [-3, 514]
    float lo = T0 + 0.5f * DT;
    float hi = T0 + ((float)NSAMP - 0.5f) * DT;
    if (fabsf(gx) > 1e-8f) {
        float ta = (PLO - cx) / gx, tb = (PHI - cx) / gx;
        lo = fmaxf(lo, fminf(ta, tb));
        hi = fminf(hi, fmaxf(ta, tb));
    } else if (cx < PLO || cx > PHI) {
        hi = lo - 1.0f;
    }
    if (fabsf(gy) > 1e-8f) {
        float ta = (PLO - cy) / gy, tb = (PHI - cy) / gy;
        lo = fmaxf(lo, fminf(ta, tb));
        hi = fminf(hi, fmaxf(ta, tb));
    } else if (cy < PLO || cy > PHI) {
        hi = lo - 1.0f;
    }

    int s_begin = 0, s_end = 0;
    if (hi >= lo) {
        s_begin = max(0, (int)floorf((lo - T0) / DT - 0.5f));
        s_end   = min(NSAMP, (int)ceilf((hi - T0) / DT - 0.5f) + 1);
    }

    float acc[NBATCH];
#pragma unroll
    for (int b = 0; b < NBATCH; ++b) acc[b] = 0.0f;

    for (int s = s_begin; s < s_end; ++s) {
        const float t  = fmaf((float)s + 0.5f, DT, T0);
        const float fx = fmaf(gx, t, cx);
        const float fy = fmaf(gy, t, cy);
        const float x0f = floorf(fx);
        const float y0f = floorf(fy);
        const float wx = fx - x0f;
        const float wy = fy - y0f;
        const int ix = (int)x0f;
        const int iy = (int)y0f;
        const float ax = 1.0f - wx;
        const float ay = 1.0f - wy;

        const bool vx0 = (unsigned)ix        < (unsigned)NPIX;
        const bool vx1 = (unsigned)(ix + 1)  < (unsigned)NPIX;
        const bool vy0 = (unsigned)iy        < (unsigned)NPIX;
        const bool vy1 = (unsigned)(iy + 1)  < (unsigned)NPIX;

        const float w00 = (vx0 && vy0) ? ax * ay : 0.0f;
        const float w01 = (vx1 && vy0) ? wx * ay : 0.0f;
        const float w10 = (vx0 && vy1) ? ax * wy : 0.0f;
        const float w11 = (vx1 && vy1) ? wx * wy : 0.0f;

        const int xc0 = min(max(ix,     0), NPIX - 1);
        const int xc1 = min(max(ix + 1, 0), NPIX - 1);
        const int yc0 = min(max(iy,     0), NPIX - 1);
        const int yc1 = min(max(iy + 1, 0), NPIX - 1);
        const int r0  = yc0 << 9;
        const int r1  = yc1 << 9;
        const int i00 = r0 + xc0, i01 = r0 + xc1;
        const int i10 = r1 + xc0, i11 = r1 + xc1;

#pragma unroll
        for (int b = 0; b < NBATCH; ++b) {
            const float* __restrict__ img = image + (size_t)b * (NPIX * NPIX);
            const float v00 = img[i00];
            const float v01 = img[i01];
            const float v10 = img[i10];
            const float v11 = img[i11];
            acc[b] = fmaf(w00, v00,
                     fmaf(w01, v01,
                     fmaf(w10, v10,
                     fmaf(w11, v11, acc[b]))));
        }
    }

#pragma unroll
    for (int b = 0; b < NBATCH; ++b) {
        out[((size_t)b * NVIEW + v) * NDET + d] = acc[b] * DT;
    }
}

extern "C" void kernel_launch(void* const* d_in, const int* in_sizes, int n_in,
                              void* d_out, int out_size, void* d_ws, size_t ws_size,
                              hipStream_t stream) {
    const float* image = (const float*)d_in[0];
    const float* views = (const float*)d_in[1];
    float* out = (float*)d_out;

    dim3 block(256, 1, 1);
    dim3 grid(NDET / 256, NVIEW, 1);
    projector_kernel<<<grid, block, 0, stream>>>(image, views, out);
}

// Round 2
// 1226.103 us; speedup vs baseline: 6.7526x; 6.7526x over previous
//
#include <hip/hip_runtime.h>

#define NPIX   512
#define NDET   768
#define NSAMP  768
#define NVIEW  360
#define NBATCH 8

// ---------------------------------------------------------------------------
// Repack image [8, 512, 512] -> packed [512, 512, 8]  (batch-innermost)
// so one bilinear corner's 8 batch values are a contiguous 32B chunk.
// ---------------------------------------------------------------------------
__global__ __launch_bounds__(256) void repack_kernel(
    const float* __restrict__ image,   // [8, 512, 512]
    float* __restrict__ packed)        // [512*512, 8]
{
    const int idx = blockIdx.x * blockDim.x + threadIdx.x;  // (y<<9)|x
    if (idx >= NPIX * NPIX) return;
    float v[NBATCH];
#pragma unroll
    for (int b = 0; b < NBATCH; ++b)
        v[b] = image[(size_t)b * (NPIX * NPIX) + idx];      // coalesced per b
    float4* p4 = (float4*)(packed + (size_t)idx * NBATCH);
    p4[0] = make_float4(v[0], v[1], v[2], v[3]);
    p4[1] = make_float4(v[4], v[5], v[6], v[7]);
}

// ---------------------------------------------------------------------------
// Main projector: one thread per (view, det); inner loop over samples;
// per sample 8x float4 loads (4 corners x 8 batches) from packed layout.
// ---------------------------------------------------------------------------
__global__ __launch_bounds__(256) void projector_kernel(
    const float* __restrict__ packed,  // [512*512, 8]
    const float* __restrict__ views,   // [360]
    float* __restrict__ out)           // [8, 360, 768]
{
    const int d = blockIdx.x * blockDim.x + threadIdx.x;
    const int v = blockIdx.y;
    if (d >= NDET) return;

    const float PIX   = 0.7433f;
    const float ISO   = 595.0f;
    const float SDD_  = 595.0f + 490.6f;          // 1085.6
    const float DGAM  = 1.2858f / SDD_;
    const float FOV   = 512.0f * 0.7433f * 0.70710678f;
    const float T0    = ISO - FOV;
    const float DT    = 2.0f * FOV / (float)NSAMP;

    const float beta  = views[v];
    const float gamma = ((float)d - 0.5f * (float)(NDET - 1)) * DGAM;
    const float sx = ISO * cosf(beta);
    const float sy = ISO * sinf(beta);
    const float ang = beta + 3.14159265358979f + gamma;
    const float dirx = cosf(ang);
    const float diry = sinf(ang);

    // pixel-space ray: fx(t) = cx + gx*t, fy(t) = cy + gy*t
    const float gx = dirx / PIX;
    const float gy = diry / PIX;
    const float cx = sx / PIX + 0.5f * (float)(NPIX - 1);
    const float cy = sy / PIX + 0.5f * (float)(NPIX - 1);

    // Clip sample range to padded image box (pad 3 px; outside contributes 0)
    const float PLO = -3.0f, PHI = (float)NPIX + 2.0f;
    float lo = T0 + 0.5f * DT;
    float hi = T0 + ((float)NSAMP - 0.5f) * DT;
    if (fabsf(gx) > 1e-8f) {
        float ta = (PLO - cx) / gx, tb = (PHI - cx) / gx;
        lo = fmaxf(lo, fminf(ta, tb));
        hi = fminf(hi, fmaxf(ta, tb));
    } else if (cx < PLO || cx > PHI) {
        hi = lo - 1.0f;
    }
    if (fabsf(gy) > 1e-8f) {
        float ta = (PLO - cy) / gy, tb = (PHI - cy) / gy;
        lo = fmaxf(lo, fminf(ta, tb));
        hi = fminf(hi, fmaxf(ta, tb));
    } else if (cy < PLO || cy > PHI) {
        hi = lo - 1.0f;
    }

    int s_begin = 0, s_end = 0;
    if (hi >= lo) {
        s_begin = max(0, (int)floorf((lo - T0) / DT - 0.5f));
        s_end   = min(NSAMP, (int)ceilf((hi - T0) / DT - 0.5f) + 1);
    }

    float acc[NBATCH];
#pragma unroll
    for (int b = 0; b < NBATCH; ++b) acc[b] = 0.0f;

    const float4* __restrict__ pk = (const float4*)packed;  // 2 float4 per pixel

    for (int s = s_begin; s < s_end; ++s) {
        const float t  = fmaf((float)s + 0.5f, DT, T0);
        const float fx = fmaf(gx, t, cx);
        const float fy = fmaf(gy, t, cy);
        const float x0f = floorf(fx);
        const float y0f = floorf(fy);
        const float wx = fx - x0f;
        const float wy = fy - y0f;
        const int ix = (int)x0f;
        const int iy = (int)y0f;
        const float ax = 1.0f - wx;
        const float ay = 1.0f - wy;

        const bool vx0 = (unsigned)ix        < (unsigned)NPIX;
        const bool vx1 = (unsigned)(ix + 1)  < (unsigned)NPIX;
        const bool vy0 = (unsigned)iy        < (unsigned)NPIX;
        const bool vy1 = (unsigned)(iy + 1)  < (unsigned)NPIX;

        const float w00 = (vx0 && vy0) ? ax * ay : 0.0f;
        const float w01 = (vx1 && vy0) ? wx * ay : 0.0f;
        const float w10 = (vx0 && vy1) ? ax * wy : 0.0f;
        const float w11 = (vx1 && vy1) ? wx * wy : 0.0f;

        const int xc0 = min(max(ix,     0), NPIX - 1);
        const int xc1 = min(max(ix + 1, 0), NPIX - 1);
        const int yc0 = min(max(iy,     0), NPIX - 1);
        const int yc1 = min(max(iy + 1, 0), NPIX - 1);
        // float4-unit index of pixel (y,x) = ((y<<9)+x)*2
        const int p00 = ((yc0 << 9) + xc0) << 1;
        const int p01 = ((yc0 << 9) + xc1) << 1;
        const int p10 = ((yc1 << 9) + xc0) << 1;
        const int p11 = ((yc1 << 9) + xc1) << 1;

        const float4 a00 = pk[p00], b00 = pk[p00 + 1];
        const float4 a01 = pk[p01], b01 = pk[p01 + 1];
        const float4 a10 = pk[p10], b10 = pk[p10 + 1];
        const float4 a11 = pk[p11], b11 = pk[p11 + 1];

        acc[0] = fmaf(w00, a00.x, fmaf(w01, a01.x, fmaf(w10, a10.x, fmaf(w11, a11.x, acc[0]))));
        acc[1] = fmaf(w00, a00.y, fmaf(w01, a01.y, fmaf(w10, a10.y, fmaf(w11, a11.y, acc[1]))));
        acc[2] = fmaf(w00, a00.z, fmaf(w01, a01.z, fmaf(w10, a10.z, fmaf(w11, a11.z, acc[2]))));
        acc[3] = fmaf(w00, a00.w, fmaf(w01, a01.w, fmaf(w10, a10.w, fmaf(w11, a11.w, acc[3]))));
        acc[4] = fmaf(w00, b00.x, fmaf(w01, b01.x, fmaf(w10, b10.x, fmaf(w11, b11.x, acc[4]))));
        acc[5] = fmaf(w00, b00.y, fmaf(w01, b01.y, fmaf(w10, b10.y, fmaf(w11, b11.y, acc[5]))));
        acc[6] = fmaf(w00, b00.z, fmaf(w01, b01.z, fmaf(w10, b10.z, fmaf(w11, b11.z, acc[6]))));
        acc[7] = fmaf(w00, b00.w, fmaf(w01, b01.w, fmaf(w10, b10.w, fmaf(w11, b11.w, acc[7]))));
    }

#pragma unroll
    for (int b = 0; b < NBATCH; ++b) {
        out[((size_t)b * NVIEW + v) * NDET + d] = acc[b] * DT;
    }
}

// ---------------------------------------------------------------------------
// Fallback (original layout, scalar loads) if ws is too small to repack.
// ---------------------------------------------------------------------------
__global__ __launch_bounds__(256) void projector_kernel_fallback(
    const float* __restrict__ image, const float* __restrict__ views,
    float* __restrict__ out)
{
    const int d = blockIdx.x * blockDim.x + threadIdx.x;
    const int v = blockIdx.y;
    if (d >= NDET) return;

    const float PIX = 0.7433f, ISO = 595.0f;
    const float SDD_ = 595.0f + 490.6f;
    const float DGAM = 1.2858f / SDD_;
    const float FOV  = 512.0f * 0.7433f * 0.70710678f;
    const float T0   = ISO - FOV;
    const float DT   = 2.0f * FOV / (float)NSAMP;

    const float beta  = views[v];
    const float gamma = ((float)d - 0.5f * (float)(NDET - 1)) * DGAM;
    const float sx = ISO * cosf(beta), sy = ISO * sinf(beta);
    const float ang = beta + 3.14159265358979f + gamma;
    const float gx = cosf(ang) / PIX, gy = sinf(ang) / PIX;
    const float cx = sx / PIX + 0.5f * (float)(NPIX - 1);
    const float cy = sy / PIX + 0.5f * (float)(NPIX - 1);

    float acc[NBATCH];
#pragma unroll
    for (int b = 0; b < NBATCH; ++b) acc[b] = 0.0f;

    for (int s = 0; s < NSAMP; ++s) {
        const float t  = fmaf((float)s + 0.5f, DT, T0);
        const float fx = fmaf(gx, t, cx);
        const float fy = fmaf(gy, t, cy);
        const float x0f = floorf(fx), y0f = floorf(fy);
        const float wx = fx - x0f, wy = fy - y0f;
        const int ix = (int)x0f, iy = (int)y0f;
        const float ax = 1.0f - wx, ay = 1.0f - wy;
        const bool vx0 = (unsigned)ix < (unsigned)NPIX;
        const bool vx1 = (unsigned)(ix + 1) < (unsigned)NPIX;
        const bool vy0 = (unsigned)iy < (unsigned)NPIX;
        const bool vy1 = (unsigned)(iy + 1) < (unsigned)NPIX;
        const float w00 = (vx0 && vy0) ? ax * ay : 0.0f;
        const float w01 = (vx1 && vy0) ? wx * ay : 0.0f;
        const float w10 = (vx0 && vy1) ? ax * wy : 0.0f;
        const float w11 = (vx1 && vy1) ? wx * wy : 0.0f;
        const int xc0 = min(max(ix, 0), NPIX - 1);
        const int xc1 = min(max(ix + 1, 0), NPIX - 1);
        const int yc0 = min(max(iy, 0), NPIX - 1);
        const int yc1 = min(max(iy + 1, 0), NPIX - 1);
        const int i00 = (yc0 << 9) + xc0, i01 = (yc0 << 9) + xc1;
        const int i10 = (yc1 << 9) + xc0, i11 = (yc1 << 9) + xc1;
#pragma unroll
        for (int b = 0; b < NBATCH; ++b) {
            const float* img = image + (size_t)b * (NPIX * NPIX);
            acc[b] = fmaf(w00, img[i00], fmaf(w01, img[i01],
                     fmaf(w10, img[i10], fmaf(w11, img[i11], acc[b]))));
        }
    }
#pragma unroll
    for (int b = 0; b < NBATCH; ++b)
        out[((size_t)b * NVIEW + v) * NDET + d] = acc[b] * DT;
}

extern "C" void kernel_launch(void* const* d_in, const int* in_sizes, int n_in,
                              void* d_out, int out_size, void* d_ws, size_t ws_size,
                              hipStream_t stream) {
    const float* image = (const float*)d_in[0];
    const float* views = (const float*)d_in[1];
    float* out = (float*)d_out;

    const size_t packed_bytes = (size_t)NPIX * NPIX * NBATCH * sizeof(float);

    if (ws_size >= packed_bytes && d_ws != nullptr) {
        float* packed = (float*)d_ws;
        repack_kernel<<<dim3((NPIX * NPIX) / 256), dim3(256), 0, stream>>>(image, packed);
        projector_kernel<<<dim3(NDET / 256, NVIEW), dim3(256), 0, stream>>>(packed, views, out);
    } else {
        projector_kernel_fallback<<<dim3(NDET / 256, NVIEW), dim3(256), 0, stream>>>(image, views, out);
    }
}

// Round 3
// 655.877 us; speedup vs baseline: 12.6234x; 1.8694x over previous
//
#include <hip/hip_runtime.h>
#include <hip/hip_fp16.h>

#define NPIX   512
#define NDET   768
#define NSAMP  768
#define NVIEW  360
#define NBATCH 8

// ---------------------------------------------------------------------------
// Repack image [8, 512, 512] fp32 -> packed fp16 [512*512, 8] (batch-innermost)
// One pixel's 8 batch values = 16 bytes = one dwordx4 load in the projector.
// ---------------------------------------------------------------------------
__global__ __launch_bounds__(256) void repack_kernel(
    const float* __restrict__ image,    // [8, 512, 512]
    __half* __restrict__ packed)        // [512*512, 8]
{
    const int idx = blockIdx.x * blockDim.x + threadIdx.x;  // (y<<9)|x
    if (idx >= NPIX * NPIX) return;
    union { __half h[8]; int4 v; } u;
#pragma unroll
    for (int b = 0; b < NBATCH; ++b)
        u.h[b] = __float2half_rn(image[(size_t)b * (NPIX * NPIX) + idx]);
    ((int4*)packed)[idx] = u.v;
}

__device__ __forceinline__ void accum_corner(const int4 raw, const float w,
                                             float acc[NBATCH]) {
    union { int4 v; __half2 h[4]; } u;
    u.v = raw;
    const float2 f0 = __half22float2(u.h[0]);
    const float2 f1 = __half22float2(u.h[1]);
    const float2 f2 = __half22float2(u.h[2]);
    const float2 f3 = __half22float2(u.h[3]);
    acc[0] = fmaf(w, f0.x, acc[0]);
    acc[1] = fmaf(w, f0.y, acc[1]);
    acc[2] = fmaf(w, f1.x, acc[2]);
    acc[3] = fmaf(w, f1.y, acc[3]);
    acc[4] = fmaf(w, f2.x, acc[4]);
    acc[5] = fmaf(w, f2.y, acc[5]);
    acc[6] = fmaf(w, f3.x, acc[6]);
    acc[7] = fmaf(w, f3.y, acc[7]);
}

// ---------------------------------------------------------------------------
// Main projector: thread = (view, det); blockIdx.z splits the sample range
// in two for 2x wave count (latency hiding + imbalance smoothing).
// Accumulates into out via atomicAdd (out zeroed before launch).
// ---------------------------------------------------------------------------
__global__ __launch_bounds__(256) void projector_kernel(
    const __half* __restrict__ packed,  // [512*512, 8]
    const float* __restrict__ views,    // [360]
    float* __restrict__ out)            // [8, 360, 768]
{
    const int d = blockIdx.x * blockDim.x + threadIdx.x;
    const int v = blockIdx.y;
    const int z = blockIdx.z;
    if (d >= NDET) return;

    const float PIX   = 0.7433f;
    const float ISO   = 595.0f;
    const float SDD_  = 595.0f + 490.6f;          // 1085.6
    const float DGAM  = 1.2858f / SDD_;
    const float FOV   = 512.0f * 0.7433f * 0.70710678f;
    const float T0    = ISO - FOV;
    const float DT    = 2.0f * FOV / (float)NSAMP;

    const float beta  = views[v];
    const float gamma = ((float)d - 0.5f * (float)(NDET - 1)) * DGAM;
    const float sx = ISO * cosf(beta);
    const float sy = ISO * sinf(beta);
    const float ang = beta + 3.14159265358979f + gamma;
    const float dirx = cosf(ang);
    const float diry = sinf(ang);

    // pixel-space ray: fx(t) = cx + gx*t, fy(t) = cy + gy*t
    const float gx = dirx / PIX;
    const float gy = diry / PIX;
    const float cx = sx / PIX + 0.5f * (float)(NPIX - 1);
    const float cy = sy / PIX + 0.5f * (float)(NPIX - 1);

    // Clip sample range to padded image box (pad 3 px; outside contributes 0)
    const float PLO = -3.0f, PHI = (float)NPIX + 2.0f;
    float lo = T0 + 0.5f * DT;
    float hi = T0 + ((float)NSAMP - 0.5f) * DT;
    if (fabsf(gx) > 1e-8f) {
        float ta = (PLO - cx) / gx, tb = (PHI - cx) / gx;
        lo = fmaxf(lo, fminf(ta, tb));
        hi = fminf(hi, fmaxf(ta, tb));
    } else if (cx < PLO || cx > PHI) {
        hi = lo - 1.0f;
    }
    if (fabsf(gy) > 1e-8f) {
        float ta = (PLO - cy) / gy, tb = (PHI - cy) / gy;
        lo = fmaxf(lo, fminf(ta, tb));
        hi = fminf(hi, fmaxf(ta, tb));
    } else if (cy < PLO || cy > PHI) {
        hi = lo - 1.0f;
    }

    int s_begin = 0, s_end = 0;
    if (hi >= lo) {
        s_begin = max(0, (int)floorf((lo - T0) / DT - 0.5f));
        s_end   = min(NSAMP, (int)ceilf((hi - T0) / DT - 0.5f) + 1);
    }

    // split [s_begin, s_end) into two chunks by blockIdx.z
    const int len  = s_end - s_begin;
    const int half = (len + 1) >> 1;
    const int cs   = s_begin + z * half;
    const int ce   = min(s_end, cs + half);

    float acc[NBATCH];
#pragma unroll
    for (int b = 0; b < NBATCH; ++b) acc[b] = 0.0f;

    const int4* __restrict__ pk = (const int4*)packed;  // one int4 per pixel

    for (int s = cs; s < ce; ++s) {
        const float t  = fmaf((float)s + 0.5f, DT, T0);
        const float fx = fmaf(gx, t, cx);
        const float fy = fmaf(gy, t, cy);
        const float x0f = floorf(fx);
        const float y0f = floorf(fy);
        const float wx = fx - x0f;
        const float wy = fy - y0f;
        const int ix = (int)x0f;
        const int iy = (int)y0f;
        const float ax = 1.0f - wx;
        const float ay = 1.0f - wy;

        const bool vx0 = (unsigned)ix        < (unsigned)NPIX;
        const bool vx1 = (unsigned)(ix + 1)  < (unsigned)NPIX;
        const bool vy0 = (unsigned)iy        < (unsigned)NPIX;
        const bool vy1 = (unsigned)(iy + 1)  < (unsigned)NPIX;

        const float w00 = (vx0 && vy0) ? ax * ay : 0.0f;
        const float w01 = (vx1 && vy0) ? wx * ay : 0.0f;
        const float w10 = (vx0 && vy1) ? ax * wy : 0.0f;
        const float w11 = (vx1 && vy1) ? wx * wy : 0.0f;

        const int xc0 = min(max(ix,     0), NPIX - 1);
        const int xc1 = min(max(ix + 1, 0), NPIX - 1);
        const int yc0 = min(max(iy,     0), NPIX - 1);
        const int yc1 = min(max(iy + 1, 0), NPIX - 1);
        const int p00 = (yc0 << 9) + xc0;
        const int p01 = (yc0 << 9) + xc1;
        const int p10 = (yc1 << 9) + xc0;
        const int p11 = (yc1 << 9) + xc1;

        const int4 r00 = pk[p00];
        const int4 r01 = pk[p01];
        const int4 r10 = pk[p10];
        const int4 r11 = pk[p11];

        accum_corner(r00, w00, acc);
        accum_corner(r01, w01, acc);
        accum_corner(r10, w10, acc);
        accum_corner(r11, w11, acc);
    }

#pragma unroll
    for (int b = 0; b < NBATCH; ++b) {
        atomicAdd(&out[((size_t)b * NVIEW + v) * NDET + d], acc[b] * DT);
    }
}

// ---------------------------------------------------------------------------
// Fallback (original layout, fp32 scalar loads) if ws is too small to repack.
// ---------------------------------------------------------------------------
__global__ __launch_bounds__(256) void projector_kernel_fallback(
    const float* __restrict__ image, const float* __restrict__ views,
    float* __restrict__ out)
{
    const int d = blockIdx.x * blockDim.x + threadIdx.x;
    const int v = blockIdx.y;
    if (d >= NDET) return;

    const float PIX = 0.7433f, ISO = 595.0f;
    const float SDD_ = 595.0f + 490.6f;
    const float DGAM = 1.2858f / SDD_;
    const float FOV  = 512.0f * 0.7433f * 0.70710678f;
    const float T0   = ISO - FOV;
    const float DT   = 2.0f * FOV / (float)NSAMP;

    const float beta  = views[v];
    const float gamma = ((float)d - 0.5f * (float)(NDET - 1)) * DGAM;
    const float sx = ISO * cosf(beta), sy = ISO * sinf(beta);
    const float ang = beta + 3.14159265358979f + gamma;
    const float gx = cosf(ang) / PIX, gy = sinf(ang) / PIX;
    const float cx = sx / PIX + 0.5f * (float)(NPIX - 1);
    const float cy = sy / PIX + 0.5f * (float)(NPIX - 1);

    float acc[NBATCH];
#pragma unroll
    for (int b = 0; b < NBATCH; ++b) acc[b] = 0.0f;

    for (int s = 0; s < NSAMP; ++s) {
        const float t  = fmaf((float)s + 0.5f, DT, T0);
        const float fx = fmaf(gx, t, cx);
        const float fy = fmaf(gy, t, cy);
        const float x0f = floorf(fx), y0f = floorf(fy);
        const float wx = fx - x0f, wy = fy - y0f;
        const int ix = (int)x0f, iy = (int)y0f;
        const float ax = 1.0f - wx, ay = 1.0f - wy;
        const bool vx0 = (unsigned)ix < (unsigned)NPIX;
        const bool vx1 = (unsigned)(ix + 1) < (unsigned)NPIX;
        const bool vy0 = (unsigned)iy < (unsigned)NPIX;
        const bool vy1 = (unsigned)(iy + 1) < (unsigned)NPIX;
        const float w00 = (vx0 && vy0) ? ax * ay : 0.0f;
        const float w01 = (vx1 && vy0) ? wx * ay : 0.0f;
        const float w10 = (vx0 && vy1) ? ax * wy : 0.0f;
        const float w11 = (vx1 && vy1) ? wx * wy : 0.0f;
        const int xc0 = min(max(ix, 0), NPIX - 1);
        const int xc1 = min(max(ix + 1, 0), NPIX - 1);
        const int yc0 = min(max(iy, 0), NPIX - 1);
        const int yc1 = min(max(iy + 1, 0), NPIX - 1);
        const int i00 = (yc0 << 9) + xc0, i01 = (yc0 << 9) + xc1;
        const int i10 = (yc1 << 9) + xc0, i11 = (yc1 << 9) + xc1;
#pragma unroll
        for (int b = 0; b < NBATCH; ++b) {
            const float* img = image + (size_t)b * (NPIX * NPIX);
            acc[b] = fmaf(w00, img[i00], fmaf(w01, img[i01],
                     fmaf(w10, img[i10], fmaf(w11, img[i11], acc[b]))));
        }
    }
#pragma unroll
    for (int b = 0; b < NBATCH; ++b)
        out[((size_t)b * NVIEW + v) * NDET + d] = acc[b] * DT;
}

extern "C" void kernel_launch(void* const* d_in, const int* in_sizes, int n_in,
                              void* d_out, int out_size, void* d_ws, size_t ws_size,
                              hipStream_t stream) {
    const float* image = (const float*)d_in[0];
    const float* views = (const float*)d_in[1];
    float* out = (float*)d_out;

    const size_t packed_bytes = (size_t)NPIX * NPIX * NBATCH * sizeof(__half);

    if (ws_size >= packed_bytes && d_ws != nullptr) {
        __half* packed = (__half*)d_ws;
        repack_kernel<<<dim3((NPIX * NPIX) / 256), dim3(256), 0, stream>>>(image, packed);
        // out is re-poisoned before every timed launch -> zero it (atomic accumulate)
        hipMemsetAsync(out, 0, (size_t)out_size * sizeof(float), stream);
        projector_kernel<<<dim3(NDET / 256, NVIEW, 2), dim3(256), 0, stream>>>(packed, views, out);
    } else {
        projector_kernel_fallback<<<dim3(NDET / 256, NVIEW), dim3(256), 0, stream>>>(image, views, out);
    }
}